// Round 3
// baseline (183.516 us; speedup 1.0000x reference)
//
#include <hip/hip_runtime.h>
#include <hip/hip_bf16.h>

// Problem constants
#define BB 4
#define LL 4096
#define DD 256
#define MM (BB * LL)              // 16384 rows total
#define NSPLIT 8                  // key-range splits per (b, qb)
#define NQB (LL / 128)            // 32 query blocks per batch (BM=128)
#define KEYS_PER_SPLIT (LL / NSPLIT)  // 512
#define KT 64                     // keys per LDS tile
#define LDS_ROW 528               // 512B row + 16B pad -> 2-way bank alias only

typedef short short8 __attribute__((ext_vector_type(8)));   // 8 bf16 (4 VGPRs)
typedef float floatx4 __attribute__((ext_vector_type(4)));

__device__ __forceinline__ unsigned short f2bf(float f) {
    __hip_bfloat16 h = __float2bfloat16(f);
    union { __hip_bfloat16 h; unsigned short s; } c; c.h = h; return c.s;
}

// ---------------------------------------------------------------------------
// Kernel 0: f32 -> bf16 conversion (for the small W matrices)
// ---------------------------------------------------------------------------
__global__ __launch_bounds__(256) void cvt_kernel(
    const float* __restrict__ src, unsigned short* __restrict__ dst, int n4)
{
    int i = blockIdx.x * 256 + threadIdx.x;
    if (i < n4) {
        const float4 v = ((const float4*)src)[i];
        ushort4 u;
        u.x = f2bf(v.x); u.y = f2bf(v.y); u.z = f2bf(v.z); u.w = f2bf(v.w);
        ((ushort4*)dst)[i] = u;
    }
}

// ---------------------------------------------------------------------------
// Kernel A: qn = l2norm(latents @ Wq^T), kn = l2norm(latents @ Wk^T), bf16 out.
// latents loaded as f32 and converted in-register. Grid: MM/64 blocks x 256
// threads (4 waves, 16 rows/wave). MFMA 16x16x32 bf16.
// A-frag: m=lane&15, k=quad*8+j. B-frag: n=lane&15, k=quad*8+j.
// C/D: col=lane&15, row=quad*4+reg (m89/m91-verified mapping).
// ---------------------------------------------------------------------------
__global__ __launch_bounds__(256) void proj_norm_kernel(
    const float* __restrict__ latents,
    const __hip_bfloat16* __restrict__ Wq,
    const __hip_bfloat16* __restrict__ Wk,
    __hip_bfloat16* __restrict__ qn,
    __hip_bfloat16* __restrict__ kn)
{
    const int tid  = threadIdx.x;
    const int wave = tid >> 6;
    const int lane = tid & 63;
    const int n15  = lane & 15;
    const int quad = lane >> 4;
    const int m0   = blockIdx.x * 64 + wave * 16;

    // A fragments for this wave's 16 rows, all of K=256 (8 chunks of 32),
    // loaded as f32 and converted to bf16 in-register.
    short8 afrag[8];
    const float* Abase = latents + (size_t)(m0 + n15) * DD + quad * 8;
#pragma unroll
    for (int kk = 0; kk < 8; ++kk) {
        const float4 v0 = *(const float4*)(Abase + kk * 32);
        const float4 v1 = *(const float4*)(Abase + kk * 32 + 4);
        short8 f;
        f[0] = (short)f2bf(v0.x); f[1] = (short)f2bf(v0.y);
        f[2] = (short)f2bf(v0.z); f[3] = (short)f2bf(v0.w);
        f[4] = (short)f2bf(v1.x); f[5] = (short)f2bf(v1.y);
        f[6] = (short)f2bf(v1.z); f[7] = (short)f2bf(v1.w);
        afrag[kk] = f;
    }

    for (int pass = 0; pass < 2; ++pass) {
        const short* W = (const short*)(pass ? Wk : Wq);
        __hip_bfloat16* out = pass ? kn : qn;

        floatx4 acc[16];
#pragma unroll
        for (int ct = 0; ct < 16; ++ct) acc[ct] = (floatx4){0.f, 0.f, 0.f, 0.f};

#pragma unroll
        for (int ct = 0; ct < 16; ++ct) {
            const short* Brow = W + (size_t)(ct * 16 + n15) * DD + quad * 8;
#pragma unroll
            for (int kk = 0; kk < 8; ++kk) {
                short8 bfr = *(const short8*)(Brow + kk * 32);
                acc[ct] = __builtin_amdgcn_mfma_f32_16x16x32_bf16(afrag[kk], bfr, acc[ct], 0, 0, 0);
            }
        }

        // Row sums of squares (rows = quad*4 + r), partial over this lane's 16 cols
        float ss[4] = {0.f, 0.f, 0.f, 0.f};
#pragma unroll
        for (int ct = 0; ct < 16; ++ct) {
#pragma unroll
            for (int r = 0; r < 4; ++r) ss[r] += acc[ct][r] * acc[ct][r];
        }
        // Reduce across the 16 lanes of the quad (xor over low 4 bits)
#pragma unroll
        for (int r = 0; r < 4; ++r) {
            ss[r] += __shfl_xor(ss[r], 1, 64);
            ss[r] += __shfl_xor(ss[r], 2, 64);
            ss[r] += __shfl_xor(ss[r], 4, 64);
            ss[r] += __shfl_xor(ss[r], 8, 64);
        }
        float sc[4];
#pragma unroll
        for (int r = 0; r < 4; ++r)
            sc[r] = 1.f / fmaxf(sqrtf(ss[r]), 1e-12f);

        // Store normalized bf16
#pragma unroll
        for (int ct = 0; ct < 16; ++ct) {
            const int col = ct * 16 + n15;
            const size_t base = (size_t)(m0 + quad * 4) * DD + col;
#pragma unroll
            for (int r = 0; r < 4; ++r)
                out[base + (size_t)r * DD] = __float2bfloat16(acc[ct][r] * sc[r]);
        }
    }
}

// ---------------------------------------------------------------------------
// Kernel B: flash-style attention sums. Each block: 128 query rows (4 waves x
// 32 rows), 512-key range. Accumulates s0=sum(e), s1=sum(e*cx), s2=sum(e*cy)
// where e = exp(10 * clip(q.k, +-5)) (clip matches ref's +-50 on scores).
// Writes per-split partials (deterministic, no atomics).
// ---------------------------------------------------------------------------
__global__ __launch_bounds__(256) void attn_kernel(
    const __hip_bfloat16* __restrict__ qn,
    const __hip_bfloat16* __restrict__ kn,
    const float* __restrict__ coords,
    float* __restrict__ partials)
{
    __shared__ char lds[KT * LDS_ROW];  // 33792 B

    const int tid  = threadIdx.x;
    const int wave = tid >> 6;
    const int lane = tid & 63;
    const int n15  = lane & 15;
    const int quad = lane >> 4;

    int bs = blockIdx.x;
    const int qb    = bs % NQB;    bs /= NQB;     // consecutive blocks share key range -> L2 locality
    const int split = bs % NSPLIT; bs /= NSPLIT;
    const int b     = bs;

    const int m_base = b * LL + qb * 128;
    const int mw     = m_base + wave * 32;

    // Q fragments: 2 row-tiles of 16 rows, K=256 (8 chunks)
    short8 aq[2][8];
#pragma unroll
    for (int rt = 0; rt < 2; ++rt) {
        const short* Qbase = (const short*)qn + (size_t)(mw + rt * 16 + n15) * DD + quad * 8;
#pragma unroll
        for (int kk = 0; kk < 8; ++kk)
            aq[rt][kk] = *(const short8*)(Qbase + kk * 32);
    }

    float s0[2][4], s1[2][4], s2[2][4];
#pragma unroll
    for (int rt = 0; rt < 2; ++rt)
#pragma unroll
        for (int r = 0; r < 4; ++r) { s0[rt][r] = 0.f; s1[rt][r] = 0.f; s2[rt][r] = 0.f; }

    const int key_base = b * LL + split * KEYS_PER_SPLIT;   // flat key row index
    const char* kbytes = (const char*)kn;
    const float SCALE = 14.426950408889634f;  // INV_TEMP * log2(e)

    for (int kt = 0; kt < KEYS_PER_SPLIT / KT; ++kt) {
        // Stage 64-key tile (64 x 256 bf16 = 32KB) into padded LDS
        const char* src = kbytes + (size_t)(key_base + kt * KT) * (DD * 2);
#pragma unroll
        for (int i = 0; i < 8; ++i) {
            const int idx = tid + i * 256;                        // 16B chunk index
            short8 v = *(const short8*)(src + (size_t)idx * 16);
            *(short8*)(&lds[(idx >> 5) * LDS_ROW + (idx & 31) * 16]) = v;
        }
        __syncthreads();

#pragma unroll
        for (int ct = 0; ct < 4; ++ct) {
            floatx4 acc0 = (floatx4){0.f, 0.f, 0.f, 0.f};
            floatx4 acc1 = (floatx4){0.f, 0.f, 0.f, 0.f};
            const char* lrow = &lds[(ct * 16 + n15) * LDS_ROW + quad * 16];
#pragma unroll
            for (int kk = 0; kk < 8; ++kk) {
                short8 bfr = *(const short8*)(lrow + kk * 64);
                acc0 = __builtin_amdgcn_mfma_f32_16x16x32_bf16(aq[0][kk], bfr, acc0, 0, 0, 0);
                acc1 = __builtin_amdgcn_mfma_f32_16x16x32_bf16(aq[1][kk], bfr, acc1, 0, 0, 0);
            }
            // coords of this lane's key column (f32 pair)
            const int kidx = key_base + kt * KT + ct * 16 + n15;
            const float2 cc = *(const float2*)(coords + (size_t)kidx * 2);
            const float cx = cc.x;
            const float cy = cc.y;
#pragma unroll
            for (int r = 0; r < 4; ++r) {
                const float a0 = fminf(fmaxf(acc0[r], -5.f), 5.f);  // ref clips scores to +-50
                const float a1 = fminf(fmaxf(acc1[r], -5.f), 5.f);
                const float e0 = exp2f(a0 * SCALE);
                const float e1 = exp2f(a1 * SCALE);
                s0[0][r] += e0; s1[0][r] += e0 * cx; s2[0][r] += e0 * cy;
                s0[1][r] += e1; s1[1][r] += e1 * cx; s2[1][r] += e1 * cy;
            }
        }
        __syncthreads();
    }

    // Reduce partial sums across the 16 lanes of each quad
#pragma unroll
    for (int rt = 0; rt < 2; ++rt) {
#pragma unroll
        for (int r = 0; r < 4; ++r) {
#pragma unroll
            for (int mask = 1; mask <= 8; mask <<= 1) {
                s0[rt][r] += __shfl_xor(s0[rt][r], mask, 64);
                s1[rt][r] += __shfl_xor(s1[rt][r], mask, 64);
                s2[rt][r] += __shfl_xor(s2[rt][r], mask, 64);
            }
        }
    }

    if (n15 == 0) {
#pragma unroll
        for (int rt = 0; rt < 2; ++rt) {
#pragma unroll
            for (int r = 0; r < 4; ++r) {
                const int m = mw + rt * 16 + quad * 4 + r;
                float* p = partials + ((size_t)split * MM + m) * 4;
                p[0] = s0[rt][r];
                p[1] = s1[rt][r];
                p[2] = s2[rt][r];
            }
        }
    }
}

// ---------------------------------------------------------------------------
// Kernel C: combine splits, apply alpha blend, emit new_coords + displacement.
// Output is f32 (reference output dtype).
// ---------------------------------------------------------------------------
__global__ __launch_bounds__(256) void finish_kernel(
    const float* __restrict__ partials,
    const float* __restrict__ coords,
    const float* __restrict__ alpha_raw,
    float* __restrict__ out)
{
    const int m = blockIdx.x * 256 + threadIdx.x;

    const float ar = alpha_raw[0];
    const float alpha = 1.f / (1.f + __expf(-ar));

    float s0 = 0.f, s1 = 0.f, s2 = 0.f;
#pragma unroll
    for (int s = 0; s < NSPLIT; ++s) {
        const float4 v = *(const float4*)(partials + ((size_t)s * MM + m) * 4);
        s0 += v.x; s1 += v.y; s2 += v.z;
    }

    const float cx = coords[m * 2];
    const float cy = coords[m * 2 + 1];
    const float inv = 1.f / s0;
    const float nx = alpha * (s1 * inv) + (1.f - alpha) * cx;
    const float ny = alpha * (s2 * inv) + (1.f - alpha) * cy;

    out[m * 2]     = nx;
    out[m * 2 + 1] = ny;
    out[2 * MM + m * 2]     = nx - cx;
    out[2 * MM + m * 2 + 1] = ny - cy;
}

extern "C" void kernel_launch(void* const* d_in, const int* in_sizes, int n_in,
                              void* d_out, int out_size, void* d_ws, size_t ws_size,
                              hipStream_t stream) {
    const float* latents   = (const float*)d_in[0];
    const float* coords    = (const float*)d_in[1];
    const float* Wq        = (const float*)d_in[2];
    const float* Wk        = (const float*)d_in[3];
    const float* alpha_raw = (const float*)d_in[4];
    // d_in[5] = layer_idx: only selects which weight set; the provided Wq/Wk
    // are already the pred_idx=1 params, so it is unused.

    char* ws = (char*)d_ws;
    __hip_bfloat16* qn   = (__hip_bfloat16*)ws;                                  // 8 MB
    __hip_bfloat16* kn   = (__hip_bfloat16*)(ws + (size_t)8 * 1024 * 1024);      // 8 MB
    __hip_bfloat16* wq_b = (__hip_bfloat16*)(ws + (size_t)16 * 1024 * 1024);     // 128 KB
    __hip_bfloat16* wk_b = (__hip_bfloat16*)(ws + (size_t)16 * 1024 * 1024 + 131072);
    float* partials      = (float*)(ws + (size_t)16 * 1024 * 1024 + 262144);     // 2 MB

    float* out = (float*)d_out;

    // f32 -> bf16 conversions for the weight matrices
    cvt_kernel<<<(DD * DD / 4 + 255) / 256, 256, 0, stream>>>(Wq, (unsigned short*)wq_b, DD * DD / 4);
    cvt_kernel<<<(DD * DD / 4 + 255) / 256, 256, 0, stream>>>(Wk, (unsigned short*)wk_b, DD * DD / 4);

    proj_norm_kernel<<<MM / 64, 256, 0, stream>>>(latents, wq_b, wk_b, qn, kn);
    attn_kernel<<<BB * NQB * NSPLIT, 256, 0, stream>>>(qn, kn, coords, partials);
    finish_kernel<<<MM / 256, 256, 0, stream>>>(partials, coords, alpha_raw, out);
}

// Round 4
// 135.086 us; speedup vs baseline: 1.3585x; 1.3585x over previous
//
#include <hip/hip_runtime.h>
#include <hip/hip_bf16.h>

// Problem constants
#define BB 4
#define LL 4096
#define DD 256
#define MM (BB * LL)              // 16384 rows total
#define NSPLIT 8
#define NQB (LL / 128)            // 32 query blocks per batch (BM=128)
#define KPS (LL / NSPLIT)         // 512 keys per split
#define KT 64                     // keys per LDS tile (64 x 512B = 32KB)

typedef short short8 __attribute__((ext_vector_type(8)));   // 8 bf16 (4 VGPRs)
typedef float floatx4 __attribute__((ext_vector_type(4)));

#define SCALE_LOG2E 14.426950408889634f   // INV_TEMP * log2(e)

__device__ __forceinline__ unsigned short f2bf(float f) {
    __hip_bfloat16 h = __float2bfloat16(f);
    union { __hip_bfloat16 h; unsigned short s; } c; c.h = h; return c.s;
}

__device__ __forceinline__ float fast_exp2(float x) {
#if __has_builtin(__builtin_amdgcn_exp2f)
    return __builtin_amdgcn_exp2f(x);
#else
    return exp2f(x);
#endif
}

// Stage 16B/lane global -> LDS. l must be the wave-uniform LDS base; HW (or
// fallback) writes lane i's 16B at l + i*16, reading g + i*16.
__device__ __forceinline__ void stage16(const char* g, char* l, int lane) {
#if __has_builtin(__builtin_amdgcn_global_load_lds)
    __builtin_amdgcn_global_load_lds(
        (const __attribute__((address_space(1))) void*)(g + lane * 16),
        (__attribute__((address_space(3))) void*)l, 16, 0, 0);
#else
    *(short8*)(l + lane * 16) = *(const short8*)(g + lane * 16);
#endif
}

// ---------------------------------------------------------------------------
// Kernel 0: W f32 -> bf16 with XOR chunk swizzle. Row r (512B = 32 chunks of
// 16B): chunk c stored at c ^ (r & 7). Makes later LDS B-fragment reads
// conflict-free while keeping rows contiguous (global_load_lds-compatible).
// 8192 threads: t -> (r = t>>5, c = t&31).
// ---------------------------------------------------------------------------
__global__ __launch_bounds__(256) void cvt_swz_kernel(
    const float* __restrict__ src, unsigned short* __restrict__ dst)
{
    const int t = blockIdx.x * 256 + threadIdx.x;
    const int r = t >> 5, c = t & 31;
    const float4 v0 = ((const float4*)src)[t * 2];
    const float4 v1 = ((const float4*)src)[t * 2 + 1];
    short8 o;
    o[0] = (short)f2bf(v0.x); o[1] = (short)f2bf(v0.y);
    o[2] = (short)f2bf(v0.z); o[3] = (short)f2bf(v0.w);
    o[4] = (short)f2bf(v1.x); o[5] = (short)f2bf(v1.y);
    o[6] = (short)f2bf(v1.z); o[7] = (short)f2bf(v1.w);
    const int cs = c ^ (r & 7);
    *(short8*)(dst + (size_t)r * DD + cs * 8) = o;
}

// ---------------------------------------------------------------------------
// Kernel A: one pass (q or k) per block. 512 blocks = (row-block, pass).
// qn = l2norm(latents @ Wq^T) * SCALE_LOG2E   (linear layout)
// kn = l2norm(latents @ Wk^T)                 (XOR-swizzled layout)
// W staged LDS-rounds of 64 rows via global_load_lds (W pre-swizzled).
// MFMA 16x16x32 bf16; A: m=lane&15,k=quad*8+j; B: n=lane&15,k=quad*8+j;
// C/D: col=lane&15,row=quad*4+reg.
// ---------------------------------------------------------------------------
__global__ __launch_bounds__(256) void proj_norm_kernel(
    const float* __restrict__ latents,
    const __hip_bfloat16* __restrict__ Wq,
    const __hip_bfloat16* __restrict__ Wk,
    __hip_bfloat16* __restrict__ qn,
    __hip_bfloat16* __restrict__ kn)
{
    __shared__ char lds[KT * 512];   // 32 KB: 64 W-rows per round

    const int tid  = threadIdx.x;
    const int wave = tid >> 6;
    const int lane = tid & 63;
    const int n15  = lane & 15;
    const int quad = lane >> 4;
    const int sw   = n15 & 7;

    const int pass = blockIdx.x & 1;
    const int rb   = blockIdx.x >> 1;
    const int m0   = rb * 64 + wave * 16;

    // A fragments: 16 rows x K=256, f32 loaded, converted in-register
    short8 afrag[8];
    const float* Abase = latents + (size_t)(m0 + n15) * DD + quad * 8;
#pragma unroll
    for (int kk = 0; kk < 8; ++kk) {
        const float4 v0 = *(const float4*)(Abase + kk * 32);
        const float4 v1 = *(const float4*)(Abase + kk * 32 + 4);
        short8 f;
        f[0] = (short)f2bf(v0.x); f[1] = (short)f2bf(v0.y);
        f[2] = (short)f2bf(v0.z); f[3] = (short)f2bf(v0.w);
        f[4] = (short)f2bf(v1.x); f[5] = (short)f2bf(v1.y);
        f[6] = (short)f2bf(v1.z); f[7] = (short)f2bf(v1.w);
        afrag[kk] = f;
    }

    const char* W = (const char*)(pass ? Wk : Wq);

    floatx4 acc[16];
#pragma unroll
    for (int ct = 0; ct < 16; ++ct) acc[ct] = (floatx4){0.f, 0.f, 0.f, 0.f};

    for (int round = 0; round < 4; ++round) {
        const char* src = W + (size_t)round * 32768 + wave * 8192;
        char* ldst = lds + wave * 8192;
#pragma unroll
        for (int j = 0; j < 8; ++j)
            stage16(src + j * 1024, ldst + j * 1024, lane);
        __syncthreads();

#pragma unroll
        for (int jt = 0; jt < 4; ++jt) {
            const int ct = round * 4 + jt;
            const char* lbase = lds + (jt * 16 + n15) * 512;
            floatx4 a = acc[ct];
#pragma unroll
            for (int kk = 0; kk < 8; ++kk) {
                const int chunk = (4 * kk + quad) ^ sw;
                short8 bfr = *(const short8*)(lbase + chunk * 16);
                a = __builtin_amdgcn_mfma_f32_16x16x32_bf16(afrag[kk], bfr, a, 0, 0, 0);
            }
            acc[ct] = a;
        }
        __syncthreads();
    }

    // Row norms (rows = quad*4 + r)
    float ss[4] = {0.f, 0.f, 0.f, 0.f};
#pragma unroll
    for (int ct = 0; ct < 16; ++ct)
#pragma unroll
        for (int r = 0; r < 4; ++r) ss[r] += acc[ct][r] * acc[ct][r];
#pragma unroll
    for (int r = 0; r < 4; ++r) {
        ss[r] += __shfl_xor(ss[r], 1, 64);
        ss[r] += __shfl_xor(ss[r], 2, 64);
        ss[r] += __shfl_xor(ss[r], 4, 64);
        ss[r] += __shfl_xor(ss[r], 8, 64);
    }
    float sc[4];
#pragma unroll
    for (int r = 0; r < 4; ++r) {
        sc[r] = 1.f / fmaxf(sqrtf(ss[r]), 1e-12f);
        if (pass == 0) sc[r] *= SCALE_LOG2E;   // fold softmax scale into qn
    }

    if (pass == 0) {
        // linear store
#pragma unroll
        for (int ct = 0; ct < 16; ++ct) {
            const int col = ct * 16 + n15;
            const size_t base = (size_t)(m0 + quad * 4) * DD + col;
#pragma unroll
            for (int r = 0; r < 4; ++r)
                qn[base + (size_t)r * DD] = __float2bfloat16(acc[ct][r] * sc[r]);
        }
    } else {
        // XOR-swizzled store: col -> chunk c=col>>3, within=col&7; c ^= row&7
#pragma unroll
        for (int ct = 0; ct < 16; ++ct) {
            const int col = ct * 16 + n15;
            const int c  = col >> 3, w8 = col & 7;
#pragma unroll
            for (int r = 0; r < 4; ++r) {
                const int row = m0 + quad * 4 + r;
                const int cs = c ^ (row & 7);
                kn[(size_t)row * DD + cs * 8 + w8] = __float2bfloat16(acc[ct][r] * sc[r]);
            }
        }
    }
}

// ---------------------------------------------------------------------------
// Kernel B: flash-style attention sums. Block = 128 q-rows x 512-key split.
// kn staged via global_load_lds (pre-swizzled, conflict-free reads).
// e = exp2(acc) directly (qn pre-scaled; clip(+-50) provably a no-op since
// |q.k| <= 1 => |score| <= 10).
// ---------------------------------------------------------------------------
__global__ __launch_bounds__(256) void attn_kernel(
    const __hip_bfloat16* __restrict__ qn,
    const __hip_bfloat16* __restrict__ kn,
    const float* __restrict__ coords,
    float* __restrict__ partials)
{
    __shared__ char lds[KT * 512];   // 32 KB

    const int tid  = threadIdx.x;
    const int wave = tid >> 6;
    const int lane = tid & 63;
    const int n15  = lane & 15;
    const int quad = lane >> 4;
    const int sw   = n15 & 7;

    int bs = blockIdx.x;
    const int qb    = bs % NQB;    bs /= NQB;
    const int split = bs % NSPLIT; bs /= NSPLIT;
    const int b     = bs;

    const int mw = b * LL + qb * 128 + wave * 32;

    // Q fragments: 2 row-tiles of 16 rows, K=256 (8 chunks) — qn is linear
    short8 aq[2][8];
#pragma unroll
    for (int rt = 0; rt < 2; ++rt) {
        const short* Qbase = (const short*)qn + (size_t)(mw + rt * 16 + n15) * DD + quad * 8;
#pragma unroll
        for (int kk = 0; kk < 8; ++kk)
            aq[rt][kk] = *(const short8*)(Qbase + kk * 32);
    }

    float s0[2][4], s1[2][4], s2[2][4];
#pragma unroll
    for (int rt = 0; rt < 2; ++rt)
#pragma unroll
        for (int r = 0; r < 4; ++r) { s0[rt][r] = 0.f; s1[rt][r] = 0.f; s2[rt][r] = 0.f; }

    const int key_base = b * LL + split * KPS;
    const char* ksrc = (const char*)kn + (size_t)key_base * 512;

    for (int kt = 0; kt < KPS / KT; ++kt) {
        // Stage 64-key tile: 4 waves x 8KB, 16B/lane contiguous
        const char* src = ksrc + (size_t)kt * KT * 512 + wave * 8192;
        char* ldst = lds + wave * 8192;
#pragma unroll
        for (int j = 0; j < 8; ++j)
            stage16(src + j * 1024, ldst + j * 1024, lane);
        __syncthreads();

#pragma unroll
        for (int ct = 0; ct < 4; ++ct) {
            const int kidx = key_base + kt * KT + ct * 16 + n15;
            const float2 cc = *(const float2*)(coords + (size_t)kidx * 2);

            floatx4 acc0 = (floatx4){0.f, 0.f, 0.f, 0.f};
            floatx4 acc1 = (floatx4){0.f, 0.f, 0.f, 0.f};
            const char* lbase = lds + (ct * 16 + n15) * 512;
#pragma unroll
            for (int kk = 0; kk < 8; ++kk) {
                const int chunk = (4 * kk + quad) ^ sw;
                short8 bfr = *(const short8*)(lbase + chunk * 16);
                acc0 = __builtin_amdgcn_mfma_f32_16x16x32_bf16(aq[0][kk], bfr, acc0, 0, 0, 0);
                acc1 = __builtin_amdgcn_mfma_f32_16x16x32_bf16(aq[1][kk], bfr, acc1, 0, 0, 0);
            }
#pragma unroll
            for (int r = 0; r < 4; ++r) {
                const float e0 = fast_exp2(acc0[r]);
                const float e1 = fast_exp2(acc1[r]);
                s0[0][r] += e0;
                s1[0][r] = fmaf(cc.x, e0, s1[0][r]);
                s2[0][r] = fmaf(cc.y, e0, s2[0][r]);
                s0[1][r] += e1;
                s1[1][r] = fmaf(cc.x, e1, s1[1][r]);
                s2[1][r] = fmaf(cc.y, e1, s2[1][r]);
            }
        }
        __syncthreads();
    }

    // Reduce across the 16 lanes of each quad
#pragma unroll
    for (int rt = 0; rt < 2; ++rt)
#pragma unroll
        for (int r = 0; r < 4; ++r)
#pragma unroll
            for (int mask = 1; mask <= 8; mask <<= 1) {
                s0[rt][r] += __shfl_xor(s0[rt][r], mask, 64);
                s1[rt][r] += __shfl_xor(s1[rt][r], mask, 64);
                s2[rt][r] += __shfl_xor(s2[rt][r], mask, 64);
            }

    if (n15 == 0) {
#pragma unroll
        for (int rt = 0; rt < 2; ++rt)
#pragma unroll
            for (int r = 0; r < 4; ++r) {
                const int m = mw + rt * 16 + quad * 4 + r;
                float* p = partials + ((size_t)split * MM + m) * 4;
                p[0] = s0[rt][r];
                p[1] = s1[rt][r];
                p[2] = s2[rt][r];
            }
    }
}

// ---------------------------------------------------------------------------
// Kernel C: combine splits, alpha blend, emit new_coords + displacement (f32).
// ---------------------------------------------------------------------------
__global__ __launch_bounds__(256) void finish_kernel(
    const float* __restrict__ partials,
    const float* __restrict__ coords,
    const float* __restrict__ alpha_raw,
    float* __restrict__ out)
{
    const int m = blockIdx.x * 256 + threadIdx.x;

    const float alpha = 1.f / (1.f + __expf(-alpha_raw[0]));

    float s0 = 0.f, s1 = 0.f, s2 = 0.f;
#pragma unroll
    for (int s = 0; s < NSPLIT; ++s) {
        const float4 v = *(const float4*)(partials + ((size_t)s * MM + m) * 4);
        s0 += v.x; s1 += v.y; s2 += v.z;
    }

    const float cx = coords[m * 2];
    const float cy = coords[m * 2 + 1];
    const float inv = 1.f / s0;
    const float nx = alpha * (s1 * inv) + (1.f - alpha) * cx;
    const float ny = alpha * (s2 * inv) + (1.f - alpha) * cy;

    out[m * 2]     = nx;
    out[m * 2 + 1] = ny;
    out[2 * MM + m * 2]     = nx - cx;
    out[2 * MM + m * 2 + 1] = ny - cy;
}

extern "C" void kernel_launch(void* const* d_in, const int* in_sizes, int n_in,
                              void* d_out, int out_size, void* d_ws, size_t ws_size,
                              hipStream_t stream) {
    const float* latents   = (const float*)d_in[0];
    const float* coords    = (const float*)d_in[1];
    const float* Wq        = (const float*)d_in[2];
    const float* Wk        = (const float*)d_in[3];
    const float* alpha_raw = (const float*)d_in[4];
    // d_in[5] = layer_idx: selects weight set only; provided W's are the
    // pred_idx=1 params, so unused.

    char* ws = (char*)d_ws;
    __hip_bfloat16* qn   = (__hip_bfloat16*)ws;                                  // 8 MB
    __hip_bfloat16* kn   = (__hip_bfloat16*)(ws + (size_t)8 * 1024 * 1024);      // 8 MB
    __hip_bfloat16* wq_b = (__hip_bfloat16*)(ws + (size_t)16 * 1024 * 1024);     // 128 KB
    __hip_bfloat16* wk_b = (__hip_bfloat16*)(ws + (size_t)16 * 1024 * 1024 + 131072);
    float* partials      = (float*)(ws + (size_t)16 * 1024 * 1024 + 262144);     // 2 MB

    float* out = (float*)d_out;

    cvt_swz_kernel<<<32, 256, 0, stream>>>(Wq, (unsigned short*)wq_b);
    cvt_swz_kernel<<<32, 256, 0, stream>>>(Wk, (unsigned short*)wk_b);
    proj_norm_kernel<<<512, 256, 0, stream>>>(latents, wq_b, wk_b, qn, kn);
    attn_kernel<<<BB * NQB * NSPLIT, 256, 0, stream>>>(qn, kn, coords, partials);
    finish_kernel<<<MM / 256, 256, 0, stream>>>(partials, coords, alpha_raw, out);
}

// Round 5
// 124.894 us; speedup vs baseline: 1.4694x; 1.0816x over previous
//
#include <hip/hip_runtime.h>
#include <hip/hip_bf16.h>

// Problem constants
#define BB 4
#define LL 4096
#define DD 256
#define MM (BB * LL)              // 16384 rows total
#define NSPLIT 4
#define NQB (LL / 128)            // 32 query blocks per batch (BM=128)
#define KPS (LL / NSPLIT)         // 1024 keys per split
#define KT 64                     // keys per LDS tile (64 x 512B = 32KB)
#define NKT (KPS / KT)            // 16

typedef short short8 __attribute__((ext_vector_type(8)));   // 8 bf16 (4 VGPRs)
typedef float floatx4 __attribute__((ext_vector_type(4)));

#define SCALE_LOG2E 14.426950408889634f   // INV_TEMP * log2(e)

__device__ __forceinline__ unsigned short f2bf(float f) {
    __hip_bfloat16 h = __float2bfloat16(f);
    union { __hip_bfloat16 h; unsigned short s; } c; c.h = h; return c.s;
}

__device__ __forceinline__ float fast_exp2(float x) {
#if __has_builtin(__builtin_amdgcn_exp2f)
    return __builtin_amdgcn_exp2f(x);
#else
    return exp2f(x);
#endif
}

// Stage 16B/lane global -> LDS (wave-uniform LDS base; lane i -> l + i*16).
__device__ __forceinline__ void stage16(const char* g, char* l, int lane) {
#if __has_builtin(__builtin_amdgcn_global_load_lds)
    __builtin_amdgcn_global_load_lds(
        (const __attribute__((address_space(1))) void*)(g + lane * 16),
        (__attribute__((address_space(3))) void*)l, 16, 0, 0);
#else
    *(short8*)(l + lane * 16) = *(const short8*)(g + lane * 16);
#endif
}

// ---------------------------------------------------------------------------
// Kernel 0: W f32 -> bf16 with XOR chunk swizzle (chunk c of row r stored at
// c ^ (r&7)). One launch converts both Wq (blocks 0..31) and Wk (32..63).
// ---------------------------------------------------------------------------
__global__ __launch_bounds__(256) void cvt_swz_kernel(
    const float* __restrict__ srcq, const float* __restrict__ srck,
    unsigned short* __restrict__ dstq, unsigned short* __restrict__ dstk)
{
    const int which = blockIdx.x >> 5;
    const float* src = which ? srck : srcq;
    unsigned short* dst = which ? dstk : dstq;
    const int t = (blockIdx.x & 31) * 256 + threadIdx.x;
    const int r = t >> 5, c = t & 31;
    const float4 v0 = ((const float4*)src)[t * 2];
    const float4 v1 = ((const float4*)src)[t * 2 + 1];
    short8 o;
    o[0] = (short)f2bf(v0.x); o[1] = (short)f2bf(v0.y);
    o[2] = (short)f2bf(v0.z); o[3] = (short)f2bf(v0.w);
    o[4] = (short)f2bf(v1.x); o[5] = (short)f2bf(v1.y);
    o[6] = (short)f2bf(v1.z); o[7] = (short)f2bf(v1.w);
    const int cs = c ^ (r & 7);
    *(short8*)(dst + (size_t)r * DD + cs * 8) = o;
}

// ---------------------------------------------------------------------------
// Kernel A: one pass (q or k) per block; 512 blocks = (row-block of 64, pass).
// qn = l2norm(lat @ Wq^T)*SCALE_LOG2E, stored FRAGMENT-MAJOR:
//   16B chunk at index ((r16*8 + kk)*4 + quad)*16 + (row&15)
//   holding q[row][kk*32+quad*8 .. +8]  (coalesced A-frag loads in attn).
// kn = l2norm(lat @ Wk^T), row-linear with XOR chunk swizzle (as staged).
// W double-buffer staged via global_load_lds; epilogue via LDS transpose.
// MFMA 16x16x32 bf16; A: m=lane&15,k=quad*8+j; B: n=lane&15,k=quad*8+j;
// C/D: col=lane&15, row=quad*4+reg.
// ---------------------------------------------------------------------------
__global__ __launch_bounds__(256) void proj_norm_kernel(
    const float* __restrict__ latents,
    const __hip_bfloat16* __restrict__ Wq,
    const __hip_bfloat16* __restrict__ Wk,
    __hip_bfloat16* __restrict__ qn,
    __hip_bfloat16* __restrict__ kn)
{
    __shared__ char lds[65536];   // 2 x 32KB W double-buffer; reused for transpose

    const int tid  = threadIdx.x;
    const int wave = tid >> 6;
    const int lane = tid & 63;
    const int n15  = lane & 15;
    const int quad = lane >> 4;
    const int sw   = n15 & 7;

    const int pass  = blockIdx.x & 1;
    const int rbase = (blockIdx.x >> 1) * 64;
    const int m0    = rbase + wave * 16;
    const int r160  = rbase >> 4;

    // A fragments: 16 rows x K=256, f32 loaded, converted in-register
    short8 afrag[8];
    const float* Abase = latents + (size_t)(m0 + n15) * DD + quad * 8;
#pragma unroll
    for (int kk = 0; kk < 8; ++kk) {
        const float4 v0 = *(const float4*)(Abase + kk * 32);
        const float4 v1 = *(const float4*)(Abase + kk * 32 + 4);
        short8 f;
        f[0] = (short)f2bf(v0.x); f[1] = (short)f2bf(v0.y);
        f[2] = (short)f2bf(v0.z); f[3] = (short)f2bf(v0.w);
        f[4] = (short)f2bf(v1.x); f[5] = (short)f2bf(v1.y);
        f[6] = (short)f2bf(v1.z); f[7] = (short)f2bf(v1.w);
        afrag[kk] = f;
    }

    const char* W = (const char*)(pass ? Wk : Wq);

    floatx4 acc[16];
#pragma unroll
    for (int ct = 0; ct < 16; ++ct) acc[ct] = (floatx4){0.f, 0.f, 0.f, 0.f};

    // Pre-stage round 0 into buf 0
    {
        const char* src = W + wave * 8192;
        char* dst = lds + wave * 8192;
#pragma unroll
        for (int j = 0; j < 8; ++j) stage16(src + j * 1024, dst + j * 1024, lane);
    }

    for (int round = 0; round < 4; ++round) {
        __syncthreads();    // own-wave vmcnt drained here -> buf (round&1) ready
        if (round + 1 < 4) {
            const char* src = W + (size_t)(round + 1) * 32768 + wave * 8192;
            char* dst = lds + ((round + 1) & 1) * 32768 + wave * 8192;
#pragma unroll
            for (int j = 0; j < 8; ++j) stage16(src + j * 1024, dst + j * 1024, lane);
        }
        const char* buf = lds + (round & 1) * 32768;
#pragma unroll
        for (int jt = 0; jt < 4; ++jt) {
            const int ct = round * 4 + jt;
            const char* lbase = buf + (jt * 16 + n15) * 512;
            floatx4 a = acc[ct];
#pragma unroll
            for (int kk = 0; kk < 8; ++kk) {
                const int chunk = (4 * kk + quad) ^ sw;
                short8 bfr = *(const short8*)(lbase + chunk * 16);
                a = __builtin_amdgcn_mfma_f32_16x16x32_bf16(afrag[kk], bfr, a, 0, 0, 0);
            }
            acc[ct] = a;
        }
    }

    // Row norms (rows = quad*4 + r)
    float ss[4] = {0.f, 0.f, 0.f, 0.f};
#pragma unroll
    for (int ct = 0; ct < 16; ++ct)
#pragma unroll
        for (int r = 0; r < 4; ++r) ss[r] += acc[ct][r] * acc[ct][r];
#pragma unroll
    for (int r = 0; r < 4; ++r) {
        ss[r] += __shfl_xor(ss[r], 1, 64);
        ss[r] += __shfl_xor(ss[r], 2, 64);
        ss[r] += __shfl_xor(ss[r], 4, 64);
        ss[r] += __shfl_xor(ss[r], 8, 64);
    }
    float sc[4];
#pragma unroll
    for (int r = 0; r < 4; ++r) {
        sc[r] = 1.f / fmaxf(sqrtf(ss[r]), 1e-12f);
        if (pass == 0) sc[r] *= SCALE_LOG2E;   // fold softmax scale into qn
    }

    // Epilogue: LDS transpose (64 rows x 136-el padded bf16) then coalesced
    // 16B stores. Two halves of 128 cols each.
    unsigned short* tb = (unsigned short*)lds;
#pragma unroll
    for (int h = 0; h < 2; ++h) {
        __syncthreads();   // previous lds users done
#pragma unroll
        for (int cth = 0; cth < 8; ++cth) {
            const int ct = h * 8 + cth;
            const int col = cth * 16 + n15;
#pragma unroll
            for (int r = 0; r < 4; ++r) {
                const int rl = wave * 16 + quad * 4 + r;
                tb[rl * 136 + col] = f2bf(acc[ct][r] * sc[r]);
            }
        }
        __syncthreads();
        if (pass == 0) {
#pragma unroll
            for (int j = 0; j < 4; ++j) {
                const int g = tid + j * 256;
                const int n15r = g & 15, q2 = (g >> 4) & 3, kkh = (g >> 6) & 3, r16l = (g >> 8) & 3;
                const int rl = r16l * 16 + n15r;
                short8 v = *(const short8*)(tb + rl * 136 + kkh * 32 + q2 * 8);
                const size_t chunk = (((size_t)(r160 + r16l) * 8 + (h * 4 + kkh)) * 4 + q2) * 16 + n15r;
                *(short8*)((char*)qn + chunk * 16) = v;
            }
        } else {
#pragma unroll
            for (int j = 0; j < 4; ++j) {
                const int g = tid + j * 256;
                const int csl = g & 15, rl = g >> 4;
                const int row = rbase + rl;
                const int ci = csl ^ (row & 7);
                short8 v = *(const short8*)(tb + rl * 136 + ci * 8);
                *(short8*)((char*)kn + (size_t)row * 512 + (h * 16 + csl) * 16) = v;
            }
        }
    }
}

// ---------------------------------------------------------------------------
// Kernel B: flash-style attention sums, double-buffered LDS staging.
// Block = 128 q-rows x 1024-key split; 512 blocks = 2/CU (64KB LDS).
// One barrier per key-tile: barrier -> issue loads for kt+1 (other buf)
// -> compute kt. e = exp2(acc) (qn pre-scaled; ref's clip(+-50) is a no-op
// since |q.k| <= 1 => |score| <= 10).
// ---------------------------------------------------------------------------
__global__ __launch_bounds__(256) void attn_kernel(
    const __hip_bfloat16* __restrict__ qn,
    const __hip_bfloat16* __restrict__ kn,
    const float* __restrict__ coords,
    float* __restrict__ partials)
{
    __shared__ char lds[2 * 32768];

    const int tid  = threadIdx.x;
    const int wave = tid >> 6;
    const int lane = tid & 63;
    const int n15  = lane & 15;
    const int quad = lane >> 4;
    const int sw   = n15 & 7;

    int bs = blockIdx.x;
    const int qb    = bs % NQB;    bs /= NQB;
    const int split = bs % NSPLIT; bs /= NSPLIT;
    const int b     = bs;

    const int mw = b * LL + qb * 128 + wave * 32;

    const int key_base = b * LL + split * KPS;
    const char* ksrc = (const char*)kn + (size_t)key_base * 512;

    // Pre-stage tile 0
    {
        const char* src = ksrc + wave * 8192;
        char* dst = lds + wave * 8192;
#pragma unroll
        for (int j = 0; j < 8; ++j) stage16(src + j * 1024, dst + j * 1024, lane);
    }

    // Q fragments from fragment-major qn: fully coalesced 16B/lane loads
    short8 aq[2][8];
    const int t16 = mw >> 4;
#pragma unroll
    for (int rt = 0; rt < 2; ++rt)
#pragma unroll
        for (int kk = 0; kk < 8; ++kk) {
            const size_t chunk = (((size_t)(t16 + rt) * 8 + kk) * 4 + quad) * 16 + n15;
            aq[rt][kk] = *(const short8*)((const char*)qn + chunk * 16);
        }

    float s0[2][4], s1[2][4], s2[2][4];
#pragma unroll
    for (int rt = 0; rt < 2; ++rt)
#pragma unroll
        for (int r = 0; r < 4; ++r) { s0[rt][r] = 0.f; s1[rt][r] = 0.f; s2[rt][r] = 0.f; }

    for (int kt = 0; kt < NKT; ++kt) {
        __syncthreads();   // own-wave vmcnt drained -> buf (kt&1) visible to all
        if (kt + 1 < NKT) {
            const char* src = ksrc + (size_t)(kt + 1) * KT * 512 + wave * 8192;
            char* dst = lds + ((kt + 1) & 1) * 32768 + wave * 8192;
#pragma unroll
            for (int j = 0; j < 8; ++j) stage16(src + j * 1024, dst + j * 1024, lane);
        }
        const char* buf = lds + (kt & 1) * 32768;

#pragma unroll
        for (int ct = 0; ct < 4; ++ct) {
            const int kidx = key_base + kt * KT + ct * 16 + n15;
            const float2 cc = *(const float2*)(coords + (size_t)kidx * 2);

            floatx4 acc0 = (floatx4){0.f, 0.f, 0.f, 0.f};
            floatx4 acc1 = (floatx4){0.f, 0.f, 0.f, 0.f};
            const char* lbase = buf + (ct * 16 + n15) * 512;
#pragma unroll
            for (int kk = 0; kk < 8; ++kk) {
                const int chunk = (4 * kk + quad) ^ sw;
                short8 bfr = *(const short8*)(lbase + chunk * 16);
                acc0 = __builtin_amdgcn_mfma_f32_16x16x32_bf16(aq[0][kk], bfr, acc0, 0, 0, 0);
                acc1 = __builtin_amdgcn_mfma_f32_16x16x32_bf16(aq[1][kk], bfr, acc1, 0, 0, 0);
            }
#pragma unroll
            for (int r = 0; r < 4; ++r) {
                const float e0 = fast_exp2(acc0[r]);
                const float e1 = fast_exp2(acc1[r]);
                s0[0][r] += e0;
                s1[0][r] = fmaf(cc.x, e0, s1[0][r]);
                s2[0][r] = fmaf(cc.y, e0, s2[0][r]);
                s0[1][r] += e1;
                s1[1][r] = fmaf(cc.x, e1, s1[1][r]);
                s2[1][r] = fmaf(cc.y, e1, s2[1][r]);
            }
        }
    }

    // Reduce across the 16 lanes of each quad
#pragma unroll
    for (int rt = 0; rt < 2; ++rt)
#pragma unroll
        for (int r = 0; r < 4; ++r)
#pragma unroll
            for (int mask = 1; mask <= 8; mask <<= 1) {
                s0[rt][r] += __shfl_xor(s0[rt][r], mask, 64);
                s1[rt][r] += __shfl_xor(s1[rt][r], mask, 64);
                s2[rt][r] += __shfl_xor(s2[rt][r], mask, 64);
            }

    if (n15 == 0) {
#pragma unroll
        for (int rt = 0; rt < 2; ++rt)
#pragma unroll
            for (int r = 0; r < 4; ++r) {
                const int m = mw + rt * 16 + quad * 4 + r;
                float* p = partials + ((size_t)split * MM + m) * 4;
                p[0] = s0[rt][r];
                p[1] = s1[rt][r];
                p[2] = s2[rt][r];
            }
    }
}

// ---------------------------------------------------------------------------
// Kernel C: combine splits, alpha blend, emit new_coords + displacement (f32).
// ---------------------------------------------------------------------------
__global__ __launch_bounds__(256) void finish_kernel(
    const float* __restrict__ partials,
    const float* __restrict__ coords,
    const float* __restrict__ alpha_raw,
    float* __restrict__ out)
{
    const int m = blockIdx.x * 256 + threadIdx.x;

    const float alpha = 1.f / (1.f + __expf(-alpha_raw[0]));

    float s0 = 0.f, s1 = 0.f, s2 = 0.f;
#pragma unroll
    for (int s = 0; s < NSPLIT; ++s) {
        const float4 v = *(const float4*)(partials + ((size_t)s * MM + m) * 4);
        s0 += v.x; s1 += v.y; s2 += v.z;
    }

    const float cx = coords[m * 2];
    const float cy = coords[m * 2 + 1];
    const float inv = 1.f / s0;
    const float nx = alpha * (s1 * inv) + (1.f - alpha) * cx;
    const float ny = alpha * (s2 * inv) + (1.f - alpha) * cy;

    out[m * 2]     = nx;
    out[m * 2 + 1] = ny;
    out[2 * MM + m * 2]     = nx - cx;
    out[2 * MM + m * 2 + 1] = ny - cy;
}

extern "C" void kernel_launch(void* const* d_in, const int* in_sizes, int n_in,
                              void* d_out, int out_size, void* d_ws, size_t ws_size,
                              hipStream_t stream) {
    const float* latents   = (const float*)d_in[0];
    const float* coords    = (const float*)d_in[1];
    const float* Wq        = (const float*)d_in[2];
    const float* Wk        = (const float*)d_in[3];
    const float* alpha_raw = (const float*)d_in[4];
    // d_in[5] = layer_idx: selects weight set only; provided W's are the
    // pred_idx=1 params, so unused.

    char* ws = (char*)d_ws;
    __hip_bfloat16* qn   = (__hip_bfloat16*)ws;                                  // 8 MB (fragment-major)
    __hip_bfloat16* kn   = (__hip_bfloat16*)(ws + (size_t)8 * 1024 * 1024);      // 8 MB (swizzled rows)
    __hip_bfloat16* wq_b = (__hip_bfloat16*)(ws + (size_t)16 * 1024 * 1024);     // 128 KB
    __hip_bfloat16* wk_b = (__hip_bfloat16*)(ws + (size_t)16 * 1024 * 1024 + 131072);
    float* partials      = (float*)(ws + (size_t)16 * 1024 * 1024 + 262144);     // 1 MB

    float* out = (float*)d_out;

    cvt_swz_kernel<<<64, 256, 0, stream>>>(Wq, Wk, (unsigned short*)wq_b, (unsigned short*)wk_b);
    proj_norm_kernel<<<512, 256, 0, stream>>>(latents, wq_b, wk_b, qn, kn);
    attn_kernel<<<BB * NQB * NSPLIT, 256, 0, stream>>>(qn, kn, coords, partials);
    finish_kernel<<<MM / 256, 256, 0, stream>>>(partials, coords, alpha_raw, out);
}